// Round 1
// 266.962 us; speedup vs baseline: 2.2081x; 2.2081x over previous
//
#include <hip/hip_runtime.h>

#define SEQ 2048
#define BATCH 2
#define HIDDEN 2048
#define NHEADS 16
#define NKV 4
#define HD 128
#define GROUP 768       // (4+2)*128
#define TPROJ 3072      // 4*768
#define NTOK (SEQ*BATCH)  // 4096

typedef __attribute__((ext_vector_type(8))) __bf16 bf16x8;
typedef __attribute__((ext_vector_type(8))) unsigned short ushort8_t;
typedef __attribute__((ext_vector_type(4))) float f32x4;

union U8cast { ushort8_t u; bf16x8 b; };
__device__ inline bf16x8 as_bf(ushort8_t u) { U8cast c; c.u = u; return c.b; }

// fp32 -> bf16 round-to-nearest-even
__device__ inline unsigned short f2bf(float f) {
    unsigned int u = __float_as_uint(f);
    return (unsigned short)((u + 0x7FFFu + ((u >> 16) & 1u)) >> 16);
}

__device__ inline ushort8_t load8_f32_bf16(const float* __restrict__ p) {
    float4 v0 = *(const float4*)p;
    float4 v1 = *(const float4*)(p + 4);
    ushort8_t u;
    u[0] = f2bf(v0.x); u[1] = f2bf(v0.y); u[2] = f2bf(v0.z); u[3] = f2bf(v0.w);
    u[4] = f2bf(v1.x); u[5] = f2bf(v1.y); u[6] = f2bf(v1.z); u[7] = f2bf(v1.w);
    return u;
}

// C[m][n] = sum_k A[m][k] * B[n][k]   (B given row-major [N][K], i.e. C = A @ B^T)
template<bool A_IS_BF16, bool OUT_BF16>
__global__ __launch_bounds__(256) void gemm_bt_kernel(
    const void* __restrict__ Av, const float* __restrict__ B,
    void* __restrict__ Cv, int M, int N, int K)
{
    __shared__ unsigned short As[128][72];   // +8 pad: breaks 128B-stride bank conflict
    __shared__ unsigned short Bs[128][72];

    const int t    = threadIdx.x;
    const int lane = t & 63;
    const int w    = t >> 6;
    const int wm   = w >> 1, wn = w & 1;
    const int l16  = lane & 15, lg = lane >> 4;
    const int m0   = blockIdx.y * 128, n0 = blockIdx.x * 128;

    f32x4 acc[4][4] = {};

    for (int k0 = 0; k0 < K; k0 += 64) {
        __syncthreads();
#pragma unroll
        for (int c = 0; c < 4; ++c) {
            int idx = c * 256 + t;
            int row = idx >> 3;
            int col = (idx & 7) * 8;
            ushort8_t u;
            if (A_IS_BF16) {
                u = *(const ushort8_t*)((const unsigned short*)Av + (size_t)(m0 + row) * K + k0 + col);
            } else {
                u = load8_f32_bf16((const float*)Av + (size_t)(m0 + row) * K + k0 + col);
            }
            *(ushort8_t*)&As[row][col] = u;
        }
#pragma unroll
        for (int c = 0; c < 4; ++c) {
            int idx = c * 256 + t;
            int row = idx >> 3;
            int col = (idx & 7) * 8;
            ushort8_t u = load8_f32_bf16(B + (size_t)(n0 + row) * K + k0 + col);
            *(ushort8_t*)&Bs[row][col] = u;
        }
        __syncthreads();

#pragma unroll
        for (int kk = 0; kk < 64; kk += 32) {
            bf16x8 a[4], bb[4];
#pragma unroll
            for (int i = 0; i < 4; ++i)
                a[i] = as_bf(*(const ushort8_t*)&As[wm * 64 + i * 16 + l16][kk + lg * 8]);
#pragma unroll
            for (int j = 0; j < 4; ++j)
                bb[j] = as_bf(*(const ushort8_t*)&Bs[wn * 64 + j * 16 + l16][kk + lg * 8]);
#pragma unroll
            for (int i = 0; i < 4; ++i)
#pragma unroll
                for (int j = 0; j < 4; ++j)
                    acc[i][j] = __builtin_amdgcn_mfma_f32_16x16x32_bf16(a[i], bb[j], acc[i][j], 0, 0, 0);
        }
    }

#pragma unroll
    for (int i = 0; i < 4; ++i)
#pragma unroll
        for (int j = 0; j < 4; ++j)
#pragma unroll
            for (int r = 0; r < 4; ++r) {
                int row = m0 + wm * 64 + i * 16 + lg * 4 + r;
                int col = n0 + wn * 64 + j * 16 + l16;
                if (OUT_BF16)
                    ((unsigned short*)Cv)[(size_t)row * N + col] = f2bf(acc[i][j][r]);
                else
                    ((float*)Cv)[(size_t)row * N + col] = acc[i][j][r];
            }
}

// V pre-transpose: vT[(bk*HD + d)*SEQ + s] = V[s,b,kvh][d], bk = b*NKV+kvh.
// Pure register 8x8 transpose per thread -- no LDS, no bank conflicts.
// grid (SEQ/128, BATCH*NKV), 256 threads.
__global__ __launch_bounds__(256) void vtrans_kernel(const unsigned short* __restrict__ qkv,
                                                     unsigned short* __restrict__ vT)
{
    const int t = threadIdx.x;
    const int s0 = blockIdx.x * 128 + (t & 15) * 8;   // 16 s-octets per 128-tile
    const int bk = blockIdx.y;
    const int b_idx = bk >> 2;
    const int voff = (bk & 3) * GROUP + 640;          // V offset within group
    const int d0 = (t >> 4) * 8;                      // 16 d-octets = 128 d
    ushort8_t in[8];
#pragma unroll
    for (int j = 0; j < 8; ++j)
        in[j] = *(const ushort8_t*)(qkv + (size_t)((s0 + j) * BATCH + b_idx) * TPROJ + voff + d0);
#pragma unroll
    for (int dd = 0; dd < 8; ++dd) {
        ushort8_t ov;
#pragma unroll
        for (int j = 0; j < 8; ++j) ov[j] = in[j][dd];
        *(ushort8_t*)(vT + (size_t)(bk * HD + d0 + dd) * SEQ + s0) = ov;
    }
}

// Flash attention, causal, GQA. KV tile = 64, K+V^T staged in LDS (conflict-free
// padded layouts), register prefetch of next tile, longest-blocks-first order.
// grid: 1024 (flattened 32 q-tiles x 32 bh), 256 threads = 4 waves x 16 q rows.
__global__ __launch_bounds__(256, 3) void attn_kernel(const unsigned short* __restrict__ qkv,
                                                      const unsigned short* __restrict__ vT,
                                                      unsigned short* __restrict__ attn_out)
{
    // Row strides 272B / 144B / 144B: 16B-aligned, not 0 mod 128B -> all b128
    // accesses verified 8-lanes-per-16B-slot (minimum phases, conflict-free).
    __shared__ __align__(16) unsigned short Ks[64][136];     // K  [kv][d]
    __shared__ __align__(16) unsigned short Vt[128][72];     // V^T[d][kv]
    __shared__ __align__(16) unsigned short Plds[4][16][72]; // per-wave P [q][kv]

    const int t    = threadIdx.x;
    const int lane = t & 63;
    const int w    = t >> 6;
    const int l16  = lane & 15, lg = lane >> 4;

    // longest-first dispatch: big qi launches first -> kills causal tail
    const int ord   = (int)gridDim.x - 1 - (int)blockIdx.x;
    const int qi    = ord >> 5;          // 0..31
    const int bh    = ord & 31;
    const int qb0   = qi * 64;
    const int b_idx = bh >> 4;
    const int h     = bh & 15;
    const int kvh   = h >> 2;
    const int qoff  = kvh * GROUP + (h & 3) * HD;
    const int koff  = kvh * GROUP + 512;
    const int vrow0 = (b_idx * NKV + kvh) * HD;

    const int qbase = qb0 + w * 16;
    const float scale = 0.08838834764831845f;  // 1/sqrt(128)

    // Q fragments (A layout): row = lane&15, k-chunk by lane>>4
    ushort8_t qf[4];
    {
        size_t qrow = (size_t)((qbase + l16) * BATCH + b_idx) * TPROJ + qoff;
#pragma unroll
        for (int kc = 0; kc < 4; ++kc)
            qf[kc] = *(const ushort8_t*)(qkv + qrow + kc * 32 + lg * 8);
    }

    f32x4 o[8] = {};
    float mstate[4], lstate[4];
#pragma unroll
    for (int r = 0; r < 4; ++r) { mstate[r] = -1e30f; lstate[r] = 0.f; }

    const int nIter = qi + 1;            // KVB=64 tiles, uniform across block

    const int kvK = t >> 4, dK = (t & 15) * 8;   // K staging coords
    const int dV  = t >> 3, kvV = (t & 7) * 8;   // V^T staging coords

    // prefetch tile 0 into registers
    ushort8_t kr[4], vr[4];
#pragma unroll
    for (int c = 0; c < 4; ++c)
        kr[c] = *(const ushort8_t*)(qkv + (size_t)((c * 16 + kvK) * BATCH + b_idx) * TPROJ + koff + dK);
#pragma unroll
    for (int c = 0; c < 4; ++c)
        vr[c] = *(const ushort8_t*)(vT + (size_t)(vrow0 + c * 32 + dV) * SEQ + kvV);

    for (int it = 0; it < nIter; ++it) {
        const int kv0 = it * 64;
        __syncthreads();                          // prior tile's LDS reads done
        // stage K tile (64 kv x 128 d) -- vectorized, conflict-free
#pragma unroll
        for (int c = 0; c < 4; ++c)
            *(ushort8_t*)&Ks[c * 16 + kvK][dK] = kr[c];
        // stage V^T tile (128 d x 64 kv) -- vectorized, conflict-free
#pragma unroll
        for (int c = 0; c < 4; ++c)
            *(ushort8_t*)&Vt[c * 32 + dV][kvV] = vr[c];
        __syncthreads();

        // issue next tile's global loads now; latency hides under compute below
        if (it + 1 < nIter) {
            const int kn = kv0 + 64;
#pragma unroll
            for (int c = 0; c < 4; ++c)
                kr[c] = *(const ushort8_t*)(qkv + (size_t)((kn + c * 16 + kvK) * BATCH + b_idx) * TPROJ + koff + dK);
#pragma unroll
            for (int c = 0; c < 4; ++c)
                vr[c] = *(const ushort8_t*)(vT + (size_t)(vrow0 + c * 32 + dV) * SEQ + kn + kvV);
        }

        // --- QK^T: S[16 q][64 kv] ---
        f32x4 s[4] = {};
        __builtin_amdgcn_s_setprio(1);
#pragma unroll
        for (int nf = 0; nf < 4; ++nf)
#pragma unroll
            for (int kc = 0; kc < 4; ++kc) {
                ushort8_t kb = *(const ushort8_t*)&Ks[nf * 16 + l16][kc * 32 + lg * 8];
                s[nf] = __builtin_amdgcn_mfma_f32_16x16x32_bf16(as_bf(qf[kc]), as_bf(kb), s[nf], 0, 0, 0);
            }
        __builtin_amdgcn_s_setprio(0);

        // --- scale + causal mask (only the diagonal tile needs masking) ---
        if (it == nIter - 1) {
#pragma unroll
            for (int nf = 0; nf < 4; ++nf)
#pragma unroll
                for (int r = 0; r < 4; ++r) {
                    int kv_g = kv0 + l16 + 16 * nf;
                    int q_g  = qbase + lg * 4 + r;
                    float v = s[nf][r] * scale;
                    s[nf][r] = (kv_g > q_g) ? -1e30f : v;
                }
        } else {
#pragma unroll
            for (int nf = 0; nf < 4; ++nf)
#pragma unroll
                for (int r = 0; r < 4; ++r) s[nf][r] *= scale;
        }

        // --- online softmax (row reduce over lane&15 groups) ---
        float rmax[4], rsum[4], corr[4];
#pragma unroll
        for (int r = 0; r < 4; ++r)
            rmax[r] = fmaxf(fmaxf(s[0][r], s[1][r]), fmaxf(s[2][r], s[3][r]));
#pragma unroll
        for (int msk = 1; msk <= 8; msk <<= 1)
#pragma unroll
            for (int r = 0; r < 4; ++r) rmax[r] = fmaxf(rmax[r], __shfl_xor(rmax[r], msk));
#pragma unroll
        for (int r = 0; r < 4; ++r) {
            float mn = fmaxf(mstate[r], rmax[r]);
            corr[r] = __expf(mstate[r] - mn);
            mstate[r] = mn;
            rsum[r] = 0.f;
        }
#pragma unroll
        for (int nf = 0; nf < 4; ++nf)
#pragma unroll
            for (int r = 0; r < 4; ++r) {
                float p = __expf(s[nf][r] - mstate[r]);
                rsum[r] += p;
                Plds[w][lg * 4 + r][l16 + 16 * nf] = f2bf(p);   // C-layout -> [q][kv]
            }
#pragma unroll
        for (int msk = 1; msk <= 8; msk <<= 1)
#pragma unroll
            for (int r = 0; r < 4; ++r) rsum[r] += __shfl_xor(rsum[r], msk);
#pragma unroll
        for (int r = 0; r < 4; ++r) lstate[r] = lstate[r] * corr[r] + rsum[r];
#pragma unroll
        for (int f = 0; f < 8; ++f)
#pragma unroll
            for (int r = 0; r < 4; ++r) o[f][r] *= corr[r];

        // --- PV: O[16 q][128 d] += P[16][64] @ V[64][128] (per-wave, no barrier) ---
        __builtin_amdgcn_s_setprio(1);
#pragma unroll
        for (int c = 0; c < 2; ++c) {
            ushort8_t pf = *(const ushort8_t*)&Plds[w][l16][c * 32 + lg * 8];
#pragma unroll
            for (int f = 0; f < 8; ++f) {
                ushort8_t vf = *(const ushort8_t*)&Vt[l16 + 16 * f][c * 32 + lg * 8];
                o[f] = __builtin_amdgcn_mfma_f32_16x16x32_bf16(as_bf(pf), as_bf(vf), o[f], 0, 0, 0);
            }
        }
        __builtin_amdgcn_s_setprio(0);
    }

    // --- epilogue: normalize and store bf16 ---
#pragma unroll
    for (int f = 0; f < 8; ++f)
#pragma unroll
        for (int r = 0; r < 4; ++r) {
            int q_g = qbase + lg * 4 + r;
            size_t row = (size_t)(q_g * BATCH + b_idx) * HIDDEN;
            attn_out[row + h * HD + 16 * f + l16] = f2bf(o[f][r] / lstate[r]);
        }
}

extern "C" void kernel_launch(void* const* d_in, const int* in_sizes, int n_in,
                              void* d_out, int out_size, void* d_ws, size_t ws_size,
                              hipStream_t stream) {
    const float* x     = (const float*)d_in[0];
    const float* wqkv  = (const float*)d_in[1];
    const float* wproj = (const float*)d_in[2];
    float* out = (float*)d_out;

    unsigned short* qkv  = (unsigned short*)d_ws;                    // [NTOK][TPROJ] bf16
    unsigned short* attn = qkv + (size_t)NTOK * TPROJ;               // [NTOK][HIDDEN] bf16
    unsigned short* vT   = attn + (size_t)NTOK * HIDDEN;             // [B*NKV*HD][SEQ] bf16

    // 1) QKV projection: qkv = x @ wqkv^T  (fp32 in, bf16 out)
    gemm_bt_kernel<false, true><<<dim3(TPROJ / 128, NTOK / 128), 256, 0, stream>>>(
        (const void*)x, wqkv, (void*)qkv, NTOK, TPROJ, HIDDEN);

    // 2) V pre-transpose (removes all scalar transpose LDS writes from attention)
    vtrans_kernel<<<dim3(SEQ / 128, BATCH * NKV), 256, 0, stream>>>(qkv, vT);

    // 3) causal GQA flash attention
    attn_kernel<<<dim3(1024), 256, 0, stream>>>(qkv, vT, attn);

    // 4) output projection: out = attn @ wproj^T  (bf16 in, fp32 out)
    gemm_bt_kernel<true, false><<<dim3(HIDDEN / 128, NTOK / 128), 256, 0, stream>>>(
        (const void*)attn, wproj, (void*)out, NTOK, HIDDEN, HIDDEN);
}

// Round 2
// 253.605 us; speedup vs baseline: 2.3244x; 1.0527x over previous
//
#include <hip/hip_runtime.h>

#define SEQ 2048
#define BATCH 2
#define HIDDEN 2048
#define NHEADS 16
#define NKV 4
#define HD 128
#define GROUP 768       // (4+2)*128
#define TPROJ 3072      // 4*768
#define NTOK (SEQ*BATCH)  // 4096

typedef __attribute__((ext_vector_type(8))) __bf16 bf16x8;
typedef __attribute__((ext_vector_type(8))) unsigned short ushort8_t;
typedef __attribute__((ext_vector_type(4))) float f32x4;

union U8cast { ushort8_t u; bf16x8 b; };
__device__ inline bf16x8 as_bf(ushort8_t u) { U8cast c; c.u = u; return c.b; }

// fp32 -> bf16 round-to-nearest-even
__device__ inline unsigned short f2bf(float f) {
    unsigned int u = __float_as_uint(f);
    return (unsigned short)((u + 0x7FFFu + ((u >> 16) & 1u)) >> 16);
}

__device__ inline ushort8_t load8_f32_bf16(const float* __restrict__ p) {
    float4 v0 = *(const float4*)p;
    float4 v1 = *(const float4*)(p + 4);
    ushort8_t u;
    u[0] = f2bf(v0.x); u[1] = f2bf(v0.y); u[2] = f2bf(v0.z); u[3] = f2bf(v0.w);
    u[4] = f2bf(v1.x); u[5] = f2bf(v1.y); u[6] = f2bf(v1.z); u[7] = f2bf(v1.w);
    return u;
}

// async global->LDS DMA, 16B per lane. LDS dest = wave-uniform base + lane*16.
__device__ inline void gload_lds16(const unsigned short* g, unsigned short* l) {
    __builtin_amdgcn_global_load_lds(
        (const __attribute__((address_space(1))) void*)g,
        (__attribute__((address_space(3))) void*)l, 16, 0, 0);
}

// fp32 -> bf16 elementwise convert, 8 elems/thread, exact grid (n % 2048 == 0)
__global__ __launch_bounds__(256) void conv_kernel(const float* __restrict__ in,
                                                   unsigned short* __restrict__ out)
{
    size_t i = (size_t)(blockIdx.x * 256 + threadIdx.x) * 8;
    *(ushort8_t*)(out + i) = load8_f32_bf16(in + i);
}

// C[m][n] = sum_k A[m][k] * B[n][k]; A,B bf16 row-major. m97 structure:
// 128x128 tile, BK=64, linear LDS, global_load_lds width=16, 2-barrier loop.
template<bool OUT_BF16>
__global__ __launch_bounds__(256) void gemm_bt_kernel(
    const unsigned short* __restrict__ A, const unsigned short* __restrict__ B,
    void* __restrict__ Cv, int M, int N, int K)
{
    __shared__ unsigned short As[128 * 64];   // linear: required by global_load_lds
    __shared__ unsigned short Bs[128 * 64];

    const int t    = threadIdx.x;
    const int lane = t & 63;
    const int w    = t >> 6;
    const int wm   = w >> 1, wn = w & 1;
    const int l16  = lane & 15, lg = lane >> 4;
    const int m0   = blockIdx.y * 128, n0 = blockIdx.x * 128;

    // staging: each wave-issue covers 8 rows x 64 cols (1KB); lane -> (lane/8, (lane&7)*8)
    const int srow = lane >> 3;
    const int scol = (lane & 7) * 8;

    f32x4 acc[4][4] = {};

    for (int k0 = 0; k0 < K; k0 += 64) {
        __syncthreads();                       // prior iter's LDS reads done
#pragma unroll
        for (int i = 0; i < 4; ++i) {
            int row = w * 32 + i * 8;          // wave-uniform LDS base row
            gload_lds16(A + (size_t)(m0 + row + srow) * K + k0 + scol, &As[row * 64]);
        }
#pragma unroll
        for (int i = 0; i < 4; ++i) {
            int row = w * 32 + i * 8;
            gload_lds16(B + (size_t)(n0 + row + srow) * K + k0 + scol, &Bs[row * 64]);
        }
        __syncthreads();                       // compiler drains vmcnt before barrier

#pragma unroll
        for (int kk = 0; kk < 64; kk += 32) {
            bf16x8 a[4], bb[4];
#pragma unroll
            for (int i = 0; i < 4; ++i)
                a[i] = as_bf(*(const ushort8_t*)&As[(wm * 64 + i * 16 + l16) * 64 + kk + lg * 8]);
#pragma unroll
            for (int j = 0; j < 4; ++j)
                bb[j] = as_bf(*(const ushort8_t*)&Bs[(wn * 64 + j * 16 + l16) * 64 + kk + lg * 8]);
#pragma unroll
            for (int i = 0; i < 4; ++i)
#pragma unroll
                for (int j = 0; j < 4; ++j)
                    acc[i][j] = __builtin_amdgcn_mfma_f32_16x16x32_bf16(a[i], bb[j], acc[i][j], 0, 0, 0);
        }
    }

    // epilogue: C/D layout col = lane&15, row = (lane>>4)*4 + r  (HW-verified)
#pragma unroll
    for (int i = 0; i < 4; ++i)
#pragma unroll
        for (int j = 0; j < 4; ++j)
#pragma unroll
            for (int r = 0; r < 4; ++r) {
                int row = m0 + wm * 64 + i * 16 + lg * 4 + r;
                int col = n0 + wn * 64 + j * 16 + l16;
                if (OUT_BF16)
                    ((unsigned short*)Cv)[(size_t)row * N + col] = f2bf(acc[i][j][r]);
                else
                    ((float*)Cv)[(size_t)row * N + col] = acc[i][j][r];
            }
}

// V pre-transpose: vT[(bk*HD + d)*SEQ + s] = V[s,b,kvh][d], bk = b*NKV+kvh.
// Pure register 8x8 transpose per thread -- no LDS, no bank conflicts.
__global__ __launch_bounds__(256) void vtrans_kernel(const unsigned short* __restrict__ qkv,
                                                     unsigned short* __restrict__ vT)
{
    const int t = threadIdx.x;
    const int s0 = blockIdx.x * 128 + (t & 15) * 8;
    const int bk = blockIdx.y;
    const int b_idx = bk >> 2;
    const int voff = (bk & 3) * GROUP + 640;
    const int d0 = (t >> 4) * 8;
    ushort8_t in[8];
#pragma unroll
    for (int j = 0; j < 8; ++j)
        in[j] = *(const ushort8_t*)(qkv + (size_t)((s0 + j) * BATCH + b_idx) * TPROJ + voff + d0);
#pragma unroll
    for (int dd = 0; dd < 8; ++dd) {
        ushort8_t ov;
#pragma unroll
        for (int j = 0; j < 8; ++j) ov[j] = in[j][dd];
        *(ushort8_t*)(vT + (size_t)(bk * HD + d0 + dd) * SEQ + s0) = ov;
    }
}

// Flash attention, causal, GQA. KV tile = 64, K+V^T staged in LDS (conflict-free
// padded layouts), register prefetch of next tile, longest-blocks-first order.
__global__ __launch_bounds__(256, 3) void attn_kernel(const unsigned short* __restrict__ qkv,
                                                      const unsigned short* __restrict__ vT,
                                                      unsigned short* __restrict__ attn_out)
{
    __shared__ __align__(16) unsigned short Ks[64][136];     // K  [kv][d]
    __shared__ __align__(16) unsigned short Vt[128][72];     // V^T[d][kv]
    __shared__ __align__(16) unsigned short Plds[4][16][72]; // per-wave P [q][kv]

    const int t    = threadIdx.x;
    const int lane = t & 63;
    const int w    = t >> 6;
    const int l16  = lane & 15, lg = lane >> 4;

    const int ord   = (int)gridDim.x - 1 - (int)blockIdx.x;
    const int qi    = ord >> 5;
    const int bh    = ord & 31;
    const int qb0   = qi * 64;
    const int b_idx = bh >> 4;
    const int h     = bh & 15;
    const int kvh   = h >> 2;
    const int qoff  = kvh * GROUP + (h & 3) * HD;
    const int koff  = kvh * GROUP + 512;
    const int vrow0 = (b_idx * NKV + kvh) * HD;

    const int qbase = qb0 + w * 16;
    const float scale = 0.08838834764831845f;  // 1/sqrt(128)

    ushort8_t qf[4];
    {
        size_t qrow = (size_t)((qbase + l16) * BATCH + b_idx) * TPROJ + qoff;
#pragma unroll
        for (int kc = 0; kc < 4; ++kc)
            qf[kc] = *(const ushort8_t*)(qkv + qrow + kc * 32 + lg * 8);
    }

    f32x4 o[8] = {};
    float mstate[4], lstate[4];
#pragma unroll
    for (int r = 0; r < 4; ++r) { mstate[r] = -1e30f; lstate[r] = 0.f; }

    const int nIter = qi + 1;

    const int kvK = t >> 4, dK = (t & 15) * 8;
    const int dV  = t >> 3, kvV = (t & 7) * 8;

    ushort8_t kr[4], vr[4];
#pragma unroll
    for (int c = 0; c < 4; ++c)
        kr[c] = *(const ushort8_t*)(qkv + (size_t)((c * 16 + kvK) * BATCH + b_idx) * TPROJ + koff + dK);
#pragma unroll
    for (int c = 0; c < 4; ++c)
        vr[c] = *(const ushort8_t*)(vT + (size_t)(vrow0 + c * 32 + dV) * SEQ + kvV);

    for (int it = 0; it < nIter; ++it) {
        const int kv0 = it * 64;
        __syncthreads();
#pragma unroll
        for (int c = 0; c < 4; ++c)
            *(ushort8_t*)&Ks[c * 16 + kvK][dK] = kr[c];
#pragma unroll
        for (int c = 0; c < 4; ++c)
            *(ushort8_t*)&Vt[c * 32 + dV][kvV] = vr[c];
        __syncthreads();

        if (it + 1 < nIter) {
            const int kn = kv0 + 64;
#pragma unroll
            for (int c = 0; c < 4; ++c)
                kr[c] = *(const ushort8_t*)(qkv + (size_t)((kn + c * 16 + kvK) * BATCH + b_idx) * TPROJ + koff + dK);
#pragma unroll
            for (int c = 0; c < 4; ++c)
                vr[c] = *(const ushort8_t*)(vT + (size_t)(vrow0 + c * 32 + dV) * SEQ + kn + kvV);
        }

        f32x4 s[4] = {};
        __builtin_amdgcn_s_setprio(1);
#pragma unroll
        for (int nf = 0; nf < 4; ++nf)
#pragma unroll
            for (int kc = 0; kc < 4; ++kc) {
                ushort8_t kb = *(const ushort8_t*)&Ks[nf * 16 + l16][kc * 32 + lg * 8];
                s[nf] = __builtin_amdgcn_mfma_f32_16x16x32_bf16(as_bf(qf[kc]), as_bf(kb), s[nf], 0, 0, 0);
            }
        __builtin_amdgcn_s_setprio(0);

        if (it == nIter - 1) {
#pragma unroll
            for (int nf = 0; nf < 4; ++nf)
#pragma unroll
                for (int r = 0; r < 4; ++r) {
                    int kv_g = kv0 + l16 + 16 * nf;
                    int q_g  = qbase + lg * 4 + r;
                    float v = s[nf][r] * scale;
                    s[nf][r] = (kv_g > q_g) ? -1e30f : v;
                }
        } else {
#pragma unroll
            for (int nf = 0; nf < 4; ++nf)
#pragma unroll
                for (int r = 0; r < 4; ++r) s[nf][r] *= scale;
        }

        float rmax[4], rsum[4], corr[4];
#pragma unroll
        for (int r = 0; r < 4; ++r)
            rmax[r] = fmaxf(fmaxf(s[0][r], s[1][r]), fmaxf(s[2][r], s[3][r]));
#pragma unroll
        for (int msk = 1; msk <= 8; msk <<= 1)
#pragma unroll
            for (int r = 0; r < 4; ++r) rmax[r] = fmaxf(rmax[r], __shfl_xor(rmax[r], msk));
#pragma unroll
        for (int r = 0; r < 4; ++r) {
            float mn = fmaxf(mstate[r], rmax[r]);
            corr[r] = __expf(mstate[r] - mn);
            mstate[r] = mn;
            rsum[r] = 0.f;
        }
#pragma unroll
        for (int nf = 0; nf < 4; ++nf)
#pragma unroll
            for (int r = 0; r < 4; ++r) {
                float p = __expf(s[nf][r] - mstate[r]);
                rsum[r] += p;
                Plds[w][lg * 4 + r][l16 + 16 * nf] = f2bf(p);
            }
#pragma unroll
        for (int msk = 1; msk <= 8; msk <<= 1)
#pragma unroll
            for (int r = 0; r < 4; ++r) rsum[r] += __shfl_xor(rsum[r], msk);
#pragma unroll
        for (int r = 0; r < 4; ++r) lstate[r] = lstate[r] * corr[r] + rsum[r];
#pragma unroll
        for (int f = 0; f < 8; ++f)
#pragma unroll
            for (int r = 0; r < 4; ++r) o[f][r] *= corr[r];

        __builtin_amdgcn_s_setprio(1);
#pragma unroll
        for (int c = 0; c < 2; ++c) {
            ushort8_t pf = *(const ushort8_t*)&Plds[w][l16][c * 32 + lg * 8];
#pragma unroll
            for (int f = 0; f < 8; ++f) {
                ushort8_t vf = *(const ushort8_t*)&Vt[l16 + 16 * f][c * 32 + lg * 8];
                o[f] = __builtin_amdgcn_mfma_f32_16x16x32_bf16(as_bf(pf), as_bf(vf), o[f], 0, 0, 0);
            }
        }
        __builtin_amdgcn_s_setprio(0);
    }

#pragma unroll
    for (int f = 0; f < 8; ++f)
#pragma unroll
        for (int r = 0; r < 4; ++r) {
            int q_g = qbase + lg * 4 + r;
            size_t row = (size_t)(q_g * BATCH + b_idx) * HIDDEN;
            attn_out[row + h * HD + 16 * f + l16] = f2bf(o[f][r] / lstate[r]);
        }
}

extern "C" void kernel_launch(void* const* d_in, const int* in_sizes, int n_in,
                              void* d_out, int out_size, void* d_ws, size_t ws_size,
                              hipStream_t stream) {
    const float* x     = (const float*)d_in[0];
    const float* wqkv  = (const float*)d_in[1];
    const float* wproj = (const float*)d_in[2];
    float* out = (float*)d_out;

    unsigned short* qkv   = (unsigned short*)d_ws;                    // [NTOK][TPROJ]
    unsigned short* attn  = qkv  + (size_t)NTOK * TPROJ;              // [NTOK][HIDDEN]
    unsigned short* vT    = attn + (size_t)NTOK * HIDDEN;             // [B*NKV*HD][SEQ]
    unsigned short* xb    = vT   + (size_t)BATCH * NKV * HD * SEQ;    // [NTOK][HIDDEN]
    unsigned short* wqkvb = xb   + (size_t)NTOK * HIDDEN;             // [TPROJ][HIDDEN]
    unsigned short* wprojb= wqkvb+ (size_t)TPROJ * HIDDEN;            // [HIDDEN][HIDDEN]

    // 0) bf16 pre-convert (enables global_load_lds DMA staging in both GEMMs)
    conv_kernel<<<dim3((NTOK * HIDDEN) / 2048), 256, 0, stream>>>(x, xb);
    conv_kernel<<<dim3((TPROJ * HIDDEN) / 2048), 256, 0, stream>>>(wqkv, wqkvb);
    conv_kernel<<<dim3((HIDDEN * HIDDEN) / 2048), 256, 0, stream>>>(wproj, wprojb);

    // 1) QKV projection: qkv = x @ wqkv^T  (bf16 in, bf16 out)
    gemm_bt_kernel<true><<<dim3(TPROJ / 128, NTOK / 128), 256, 0, stream>>>(
        xb, wqkvb, (void*)qkv, NTOK, TPROJ, HIDDEN);

    // 2) V pre-transpose
    vtrans_kernel<<<dim3(SEQ / 128, BATCH * NKV), 256, 0, stream>>>(qkv, vT);

    // 3) causal GQA flash attention
    attn_kernel<<<dim3(1024), 256, 0, stream>>>(qkv, vT, attn);

    // 4) output projection: out = attn @ wproj^T  (bf16 in, fp32 out)
    gemm_bt_kernel<false><<<dim3(HIDDEN / 128, NTOK / 128), 256, 0, stream>>>(
        attn, wprojb, (void*)out, NTOK, HIDDEN, HIDDEN);
}

// Round 3
// 223.640 us; speedup vs baseline: 2.6359x; 1.1340x over previous
//
#include <hip/hip_runtime.h>

#define SEQ 2048
#define BATCH 2
#define HIDDEN 2048
#define NHEADS 16
#define NKV 4
#define HD 128
#define GROUP 768       // (4+2)*128
#define TPROJ 3072      // 4*768
#define NTOK (SEQ*BATCH)  // 4096

typedef __attribute__((ext_vector_type(8))) __bf16 bf16x8;
typedef __attribute__((ext_vector_type(8))) unsigned short ushort8_t;
typedef __attribute__((ext_vector_type(4))) float f32x4;

union U8cast { ushort8_t u; bf16x8 b; };
__device__ inline bf16x8 as_bf(ushort8_t u) { U8cast c; c.u = u; return c.b; }

// fp32 -> bf16 round-to-nearest-even
__device__ inline unsigned short f2bf(float f) {
    unsigned int u = __float_as_uint(f);
    return (unsigned short)((u + 0x7FFFu + ((u >> 16) & 1u)) >> 16);
}

__device__ inline ushort8_t load8_f32_bf16(const float* __restrict__ p) {
    float4 v0 = *(const float4*)p;
    float4 v1 = *(const float4*)(p + 4);
    ushort8_t u;
    u[0] = f2bf(v0.x); u[1] = f2bf(v0.y); u[2] = f2bf(v0.z); u[3] = f2bf(v0.w);
    u[4] = f2bf(v1.x); u[5] = f2bf(v1.y); u[6] = f2bf(v1.z); u[7] = f2bf(v1.w);
    return u;
}

// async global->LDS DMA, 16B per lane. LDS dest = wave-uniform base + lane*16.
__device__ inline void gload_lds16(const unsigned short* g, unsigned short* l) {
    __builtin_amdgcn_global_load_lds(
        (const __attribute__((address_space(1))) void*)g,
        (__attribute__((address_space(3))) void*)l, 16, 0, 0);
}

// fp32 -> bf16 elementwise convert, 8 elems/thread, exact grid (n % 2048 == 0)
__global__ __launch_bounds__(256) void conv_kernel(const float* __restrict__ in,
                                                   unsigned short* __restrict__ out)
{
    size_t i = (size_t)(blockIdx.x * 256 + threadIdx.x) * 8;
    *(ushort8_t*)(out + i) = load8_f32_bf16(in + i);
}

// ===========================================================================
// 256x256 8-phase GEMM: C[m][n] = sum_k A[m][k]*B[n][k], A,B bf16 row-major.
// 512 threads = 8 waves (2M x 4N), per-wave C = 128x64. BK=64, double-buffered
// 128 KiB LDS. Counted vmcnt(8) (never 0 in main loop), XOR-swizzled LDS slots
// staged via pre-swizzled GLOBAL addresses (linear LDS dest), raw s_barrier.
// Schedule per K-tile kt (reads buf=kt&1, stages tile kt+2 into same buf):
//   [vmcnt(8); bar]  ph0: read a0,b0 -> Q0   ph1: read b1 -> Q1
//   [bar; stage B(kt+2)]  ph2: read a1 -> Q2
//   [bar; stage A(kt+2)]  ph3: Q3 (register-only)
// Proof: stages land >=2 blocks before their reads (vmcnt(8) = 1 tile of 8
// loads pending); each LDS region is overwritten >=1 barrier after last read.
// ===========================================================================
template<bool OUT_BF16>
__global__ __launch_bounds__(512, 2) void gemm256_kernel(
    const unsigned short* __restrict__ A, const unsigned short* __restrict__ B,
    void* __restrict__ Cv, int M, int N, int K)
{
    __shared__ unsigned short lds[2][2][256 * 64];   // [buf][0=A,1=B], 128 KiB

    const int t = threadIdx.x, lane = t & 63, w = t >> 6;
    const int wm = w >> 2, wn = w & 3;
    const int l16 = lane & 15, lg = lane >> 4;

    // XCD-aware bijective swizzle (gridDim.x % 8 == 0 by construction)
    const int cpx = (int)gridDim.x >> 3;
    const int wg  = ((int)blockIdx.x & 7) * cpx + ((int)blockIdx.x >> 3);
    const int nbn = N >> 8;
    const int m0 = (wg / nbn) << 8, n0 = (wg % nbn) << 8;
    const int NKT = K >> 6;

    // staging lane coords: lane covers row lane>>3, phys slot lane&7.
    // pre-swizzled source: phys slot p of row r holds global slot p^(r&7).
    const int srow = lane >> 3;
    const int scol = ((lane & 7) ^ srow) << 3;

    f32x4 acc[8][4] = {};

    auto stage = [&](const unsigned short* __restrict__ G, int g0, int kt, int op) {
        const int k0 = kt << 6;
        unsigned short* Ld = lds[kt & 1][op];
#pragma unroll
        for (int i = 0; i < 4; ++i) {
            const int r = w * 32 + i * 8;              // wave-uniform LDS row base
            gload_lds16(G + (size_t)(g0 + r + srow) * K + k0 + scol, Ld + r * 64);
        }
    };

    // prologue: tiles 0 and 1 in flight (16 loads/wave)
    stage(A, m0, 0, 0); stage(B, n0, 0, 1);
    stage(A, m0, 1, 0); stage(B, n0, 1, 1);

    for (int kt = 0; kt < NKT; ++kt) {
        const unsigned short* As_ = lds[kt & 1][0];
        const unsigned short* Bs_ = lds[kt & 1][1];

        if (kt < NKT - 1) asm volatile("s_waitcnt vmcnt(8)" ::: "memory");
        else              asm volatile("s_waitcnt vmcnt(0)" ::: "memory");
        __builtin_amdgcn_sched_barrier(0);
        __builtin_amdgcn_s_barrier();
        __builtin_amdgcn_sched_barrier(0);

        bf16x8 aR[8], b0R[4], b1R[4];

        // ---- phase 0: read a0(8) + b0(4); MFMA Q0 = (a0,b0) ----
#pragma unroll
        for (int i = 0; i < 4; ++i)
#pragma unroll
            for (int s = 0; s < 2; ++s) {
                int row  = wm * 128 + i * 16 + l16;
                int slot = ((s << 2) | lg) ^ (l16 & 7);
                aR[i * 2 + s] = as_bf(*(const ushort8_t*)&As_[row * 64 + slot * 8]);
            }
#pragma unroll
        for (int j = 0; j < 2; ++j)
#pragma unroll
            for (int s = 0; s < 2; ++s) {
                int row  = wn * 64 + j * 16 + l16;
                int slot = ((s << 2) | lg) ^ (l16 & 7);
                b0R[j * 2 + s] = as_bf(*(const ushort8_t*)&Bs_[row * 64 + slot * 8]);
            }
        __builtin_amdgcn_s_setprio(1);
#pragma unroll
        for (int i = 0; i < 4; ++i)
#pragma unroll
            for (int j = 0; j < 2; ++j)
#pragma unroll
                for (int s = 0; s < 2; ++s)
                    acc[i][j] = __builtin_amdgcn_mfma_f32_16x16x32_bf16(aR[i*2+s], b0R[j*2+s], acc[i][j], 0, 0, 0);
        __builtin_amdgcn_s_setprio(0);

        // ---- phase 1: read b1(4); MFMA Q1 = (a0,b1) ----
#pragma unroll
        for (int j = 0; j < 2; ++j)
#pragma unroll
            for (int s = 0; s < 2; ++s) {
                int row  = wn * 64 + 32 + j * 16 + l16;
                int slot = ((s << 2) | lg) ^ (l16 & 7);
                b1R[j * 2 + s] = as_bf(*(const ushort8_t*)&Bs_[row * 64 + slot * 8]);
            }
        __builtin_amdgcn_s_setprio(1);
#pragma unroll
        for (int i = 0; i < 4; ++i)
#pragma unroll
            for (int j = 0; j < 2; ++j)
#pragma unroll
                for (int s = 0; s < 2; ++s)
                    acc[i][2 + j] = __builtin_amdgcn_mfma_f32_16x16x32_bf16(aR[i*2+s], b1R[j*2+s], acc[i][2 + j], 0, 0, 0);
        __builtin_amdgcn_s_setprio(0);

        // B-region of buf dead (b0,b1 reads retired before Q0/Q1 MFMAs)
        __builtin_amdgcn_sched_barrier(0);
        __builtin_amdgcn_s_barrier();
        __builtin_amdgcn_sched_barrier(0);
        if (kt + 2 < NKT) stage(B, n0, kt + 2, 1);
        __builtin_amdgcn_sched_barrier(0);

        // ---- phase 2: read a1(8); MFMA Q2 = (a1,b1) ----
#pragma unroll
        for (int i = 0; i < 4; ++i)
#pragma unroll
            for (int s = 0; s < 2; ++s) {
                int row  = wm * 128 + 64 + i * 16 + l16;
                int slot = ((s << 2) | lg) ^ (l16 & 7);
                aR[i * 2 + s] = as_bf(*(const ushort8_t*)&As_[row * 64 + slot * 8]);
            }
        __builtin_amdgcn_s_setprio(1);
#pragma unroll
        for (int i = 0; i < 4; ++i)
#pragma unroll
            for (int j = 0; j < 2; ++j)
#pragma unroll
                for (int s = 0; s < 2; ++s)
                    acc[4 + i][2 + j] = __builtin_amdgcn_mfma_f32_16x16x32_bf16(aR[i*2+s], b1R[j*2+s], acc[4 + i][2 + j], 0, 0, 0);
        __builtin_amdgcn_s_setprio(0);

        // A-region of buf dead (a0,a1 reads retired)
        __builtin_amdgcn_sched_barrier(0);
        __builtin_amdgcn_s_barrier();
        __builtin_amdgcn_sched_barrier(0);
        if (kt + 2 < NKT) stage(A, m0, kt + 2, 0);
        __builtin_amdgcn_sched_barrier(0);

        // ---- phase 3: MFMA Q3 = (a1,b0), register-only ----
        __builtin_amdgcn_s_setprio(1);
#pragma unroll
        for (int i = 0; i < 4; ++i)
#pragma unroll
            for (int j = 0; j < 2; ++j)
#pragma unroll
                for (int s = 0; s < 2; ++s)
                    acc[4 + i][j] = __builtin_amdgcn_mfma_f32_16x16x32_bf16(aR[i*2+s], b0R[j*2+s], acc[4 + i][j], 0, 0, 0);
        __builtin_amdgcn_s_setprio(0);
    }

    // epilogue: C/D layout col = lane&15, row = (lane>>4)*4 + r (HW-verified)
#pragma unroll
    for (int ia = 0; ia < 8; ++ia)
#pragma unroll
        for (int jb = 0; jb < 4; ++jb)
#pragma unroll
            for (int r = 0; r < 4; ++r) {
                int row = m0 + wm * 128 + (ia >> 2) * 64 + (ia & 3) * 16 + lg * 4 + r;
                int col = n0 + wn * 64 + (jb >> 1) * 32 + (jb & 1) * 16 + l16;
                if (OUT_BF16)
                    ((unsigned short*)Cv)[(size_t)row * N + col] = f2bf(acc[ia][jb][r]);
                else
                    ((float*)Cv)[(size_t)row * N + col] = acc[ia][jb][r];
            }
}

// V pre-transpose: vT[(bk*HD + d)*SEQ + s] = V[s,b,kvh][d], bk = b*NKV+kvh.
__global__ __launch_bounds__(256) void vtrans_kernel(const unsigned short* __restrict__ qkv,
                                                     unsigned short* __restrict__ vT)
{
    const int t = threadIdx.x;
    const int s0 = blockIdx.x * 128 + (t & 15) * 8;
    const int bk = blockIdx.y;
    const int b_idx = bk >> 2;
    const int voff = (bk & 3) * GROUP + 640;
    const int d0 = (t >> 4) * 8;
    ushort8_t in[8];
#pragma unroll
    for (int j = 0; j < 8; ++j)
        in[j] = *(const ushort8_t*)(qkv + (size_t)((s0 + j) * BATCH + b_idx) * TPROJ + voff + d0);
#pragma unroll
    for (int dd = 0; dd < 8; ++dd) {
        ushort8_t ov;
#pragma unroll
        for (int j = 0; j < 8; ++j) ov[j] = in[j][dd];
        *(ushort8_t*)(vT + (size_t)(bk * HD + d0 + dd) * SEQ + s0) = ov;
    }
}

// Flash attention, causal, GQA. KV tile = 64, K+V^T staged in LDS (conflict-free
// padded layouts), register prefetch of next tile, longest-blocks-first order.
__global__ __launch_bounds__(256, 3) void attn_kernel(const unsigned short* __restrict__ qkv,
                                                      const unsigned short* __restrict__ vT,
                                                      unsigned short* __restrict__ attn_out)
{
    __shared__ __align__(16) unsigned short Ks[64][136];     // K  [kv][d]
    __shared__ __align__(16) unsigned short Vt[128][72];     // V^T[d][kv]
    __shared__ __align__(16) unsigned short Plds[4][16][72]; // per-wave P [q][kv]

    const int t    = threadIdx.x;
    const int lane = t & 63;
    const int w    = t >> 6;
    const int l16  = lane & 15, lg = lane >> 4;

    const int ord   = (int)gridDim.x - 1 - (int)blockIdx.x;
    const int qi    = ord >> 5;
    const int bh    = ord & 31;
    const int qb0   = qi * 64;
    const int b_idx = bh >> 4;
    const int h     = bh & 15;
    const int kvh   = h >> 2;
    const int qoff  = kvh * GROUP + (h & 3) * HD;
    const int koff  = kvh * GROUP + 512;
    const int vrow0 = (b_idx * NKV + kvh) * HD;

    const int qbase = qb0 + w * 16;
    const float scale = 0.08838834764831845f;  // 1/sqrt(128)

    ushort8_t qf[4];
    {
        size_t qrow = (size_t)((qbase + l16) * BATCH + b_idx) * TPROJ + qoff;
#pragma unroll
        for (int kc = 0; kc < 4; ++kc)
            qf[kc] = *(const ushort8_t*)(qkv + qrow + kc * 32 + lg * 8);
    }

    f32x4 o[8] = {};
    float mstate[4], lstate[4];
#pragma unroll
    for (int r = 0; r < 4; ++r) { mstate[r] = -1e30f; lstate[r] = 0.f; }

    const int nIter = qi + 1;

    const int kvK = t >> 4, dK = (t & 15) * 8;
    const int dV  = t >> 3, kvV = (t & 7) * 8;

    ushort8_t kr[4], vr[4];
#pragma unroll
    for (int c = 0; c < 4; ++c)
        kr[c] = *(const ushort8_t*)(qkv + (size_t)((c * 16 + kvK) * BATCH + b_idx) * TPROJ + koff + dK);
#pragma unroll
    for (int c = 0; c < 4; ++c)
        vr[c] = *(const ushort8_t*)(vT + (size_t)(vrow0 + c * 32 + dV) * SEQ + kvV);

    for (int it = 0; it < nIter; ++it) {
        const int kv0 = it * 64;
        __syncthreads();
#pragma unroll
        for (int c = 0; c < 4; ++c)
            *(ushort8_t*)&Ks[c * 16 + kvK][dK] = kr[c];
#pragma unroll
        for (int c = 0; c < 4; ++c)
            *(ushort8_t*)&Vt[c * 32 + dV][kvV] = vr[c];
        __syncthreads();

        if (it + 1 < nIter) {
            const int kn = kv0 + 64;
#pragma unroll
            for (int c = 0; c < 4; ++c)
                kr[c] = *(const ushort8_t*)(qkv + (size_t)((kn + c * 16 + kvK) * BATCH + b_idx) * TPROJ + koff + dK);
#pragma unroll
            for (int c = 0; c < 4; ++c)
                vr[c] = *(const ushort8_t*)(vT + (size_t)(vrow0 + c * 32 + dV) * SEQ + kn + kvV);
        }

        f32x4 s[4] = {};
        __builtin_amdgcn_s_setprio(1);
#pragma unroll
        for (int nf = 0; nf < 4; ++nf)
#pragma unroll
            for (int kc = 0; kc < 4; ++kc) {
                ushort8_t kb = *(const ushort8_t*)&Ks[nf * 16 + l16][kc * 32 + lg * 8];
                s[nf] = __builtin_amdgcn_mfma_f32_16x16x32_bf16(as_bf(qf[kc]), as_bf(kb), s[nf], 0, 0, 0);
            }
        __builtin_amdgcn_s_setprio(0);

        if (it == nIter - 1) {
#pragma unroll
            for (int nf = 0; nf < 4; ++nf)
#pragma unroll
                for (int r = 0; r < 4; ++r) {
                    int kv_g = kv0 + l16 + 16 * nf;
                    int q_g  = qbase + lg * 4 + r;
                    float v = s[nf][r] * scale;
                    s[nf][r] = (kv_g > q_g) ? -1e30f : v;
                }
        } else {
#pragma unroll
            for (int nf = 0; nf < 4; ++nf)
#pragma unroll
                for (int r = 0; r < 4; ++r) s[nf][r] *= scale;
        }

        float rmax[4], rsum[4], corr[4];
#pragma unroll
        for (int r = 0; r < 4; ++r)
            rmax[r] = fmaxf(fmaxf(s[0][r], s[1][r]), fmaxf(s[2][r], s[3][r]));
#pragma unroll
        for (int msk = 1; msk <= 8; msk <<= 1)
#pragma unroll
            for (int r = 0; r < 4; ++r) rmax[r] = fmaxf(rmax[r], __shfl_xor(rmax[r], msk));
#pragma unroll
        for (int r = 0; r < 4; ++r) {
            float mn = fmaxf(mstate[r], rmax[r]);
            corr[r] = __expf(mstate[r] - mn);
            mstate[r] = mn;
            rsum[r] = 0.f;
        }
#pragma unroll
        for (int nf = 0; nf < 4; ++nf)
#pragma unroll
            for (int r = 0; r < 4; ++r) {
                float p = __expf(s[nf][r] - mstate[r]);
                rsum[r] += p;
                Plds[w][lg * 4 + r][l16 + 16 * nf] = f2bf(p);
            }
#pragma unroll
        for (int msk = 1; msk <= 8; msk <<= 1)
#pragma unroll
            for (int r = 0; r < 4; ++r) rsum[r] += __shfl_xor(rsum[r], msk);
#pragma unroll
        for (int r = 0; r < 4; ++r) lstate[r] = lstate[r] * corr[r] + rsum[r];
#pragma unroll
        for (int f = 0; f < 8; ++f)
#pragma unroll
            for (int r = 0; r < 4; ++r) o[f][r] *= corr[r];

        __builtin_amdgcn_s_setprio(1);
#pragma unroll
        for (int c = 0; c < 2; ++c) {
            ushort8_t pf = *(const ushort8_t*)&Plds[w][l16][c * 32 + lg * 8];
#pragma unroll
            for (int f = 0; f < 8; ++f) {
                ushort8_t vf = *(const ushort8_t*)&Vt[l16 + 16 * f][c * 32 + lg * 8];
                o[f] = __builtin_amdgcn_mfma_f32_16x16x32_bf16(as_bf(pf), as_bf(vf), o[f], 0, 0, 0);
            }
        }
        __builtin_amdgcn_s_setprio(0);
    }

#pragma unroll
    for (int f = 0; f < 8; ++f)
#pragma unroll
        for (int r = 0; r < 4; ++r) {
            int q_g = qbase + lg * 4 + r;
            size_t row = (size_t)(q_g * BATCH + b_idx) * HIDDEN;
            attn_out[row + h * HD + 16 * f + l16] = f2bf(o[f][r] / lstate[r]);
        }
}

extern "C" void kernel_launch(void* const* d_in, const int* in_sizes, int n_in,
                              void* d_out, int out_size, void* d_ws, size_t ws_size,
                              hipStream_t stream) {
    const float* x     = (const float*)d_in[0];
    const float* wqkv  = (const float*)d_in[1];
    const float* wproj = (const float*)d_in[2];
    float* out = (float*)d_out;

    unsigned short* qkv   = (unsigned short*)d_ws;                    // [NTOK][TPROJ]
    unsigned short* attn  = qkv  + (size_t)NTOK * TPROJ;              // [NTOK][HIDDEN]
    unsigned short* vT    = attn + (size_t)NTOK * HIDDEN;             // [B*NKV*HD][SEQ]
    unsigned short* xb    = vT   + (size_t)BATCH * NKV * HD * SEQ;    // [NTOK][HIDDEN]
    unsigned short* wqkvb = xb   + (size_t)NTOK * HIDDEN;             // [TPROJ][HIDDEN]
    unsigned short* wprojb= wqkvb+ (size_t)TPROJ * HIDDEN;            // [HIDDEN][HIDDEN]

    // 0) bf16 pre-convert (enables global_load_lds DMA staging in both GEMMs)
    conv_kernel<<<dim3((NTOK * HIDDEN) / 2048), 256, 0, stream>>>(x, xb);
    conv_kernel<<<dim3((TPROJ * HIDDEN) / 2048), 256, 0, stream>>>(wqkv, wqkvb);
    conv_kernel<<<dim3((HIDDEN * HIDDEN) / 2048), 256, 0, stream>>>(wproj, wprojb);

    // 1) QKV projection: qkv = x @ wqkv^T  (bf16 in, bf16 out). 192 blocks (%8==0)
    gemm256_kernel<true><<<dim3((NTOK / 256) * (TPROJ / 256)), 512, 0, stream>>>(
        xb, wqkvb, (void*)qkv, NTOK, TPROJ, HIDDEN);

    // 2) V pre-transpose
    vtrans_kernel<<<dim3(SEQ / 128, BATCH * NKV), 256, 0, stream>>>(qkv, vT);

    // 3) causal GQA flash attention
    attn_kernel<<<dim3(1024), 256, 0, stream>>>(qkv, vT, attn);

    // 4) output projection: out = attn @ wproj^T  (bf16 in, fp32 out). 128 blocks
    gemm256_kernel<false><<<dim3((NTOK / 256) * (HIDDEN / 256)), 512, 0, stream>>>(
        attn, wprojb, (void*)out, NTOK, HIDDEN, HIDDEN);
}